// Round 5
// baseline (225.158 us; speedup 1.0000x reference)
//
#include <hip/hip_runtime.h>

#define B_ 32
#define CI 128
#define CO 256
#define K_DIM 1152            // 9*128
#define M_DIM 100352          // 32*56*56
#define BM 256
#define BN 256
#define NSLOT 36              // K_DIM / 32 (K-half slots, ring of 4 in LDS)
#define HPAD 58               // 56 + halo
#define XB_OFF 589824         // byte offset of xb in ws (after wt: 1152*256*2 B)
#define WTBLK 72              // (K_DIM/64)*(CO/64) transpose tiles
#define XPBLK 6728            // (B_*HPAD*HPAD*16)/256 pad blocks
#define GRID_M 392            // M_DIM / BM = 49*8 (divisible by 8 XCDs)

typedef float          floatx4  __attribute__((ext_vector_type(4)));
typedef unsigned short ushortx8 __attribute__((ext_vector_type(8)));
typedef __bf16         bf16x8   __attribute__((ext_vector_type(8)));

typedef __attribute__((address_space(1))) void gas_void;
typedef __attribute__((address_space(3))) void las_void;
#define GLD16(g, l) __builtin_amdgcn_global_load_lds( \
    (gas_void*)(uintptr_t)(g), (las_void*)(l), 16, 0, 0)

__device__ __forceinline__ unsigned short bf16_rne(float f) {
    unsigned u = __builtin_bit_cast(unsigned, f);
    u += 0x7FFFu + ((u >> 16) & 1u);
    return (unsigned short)(u >> 16);
}

// ---- fused prepass: blocks [0,72) transpose w -> wt bf16 [256][1152];
//      blocks [72, 72+6728) pad x -> xb bf16 [32][58][58][128] with zero halo.
__global__ void prepass_kernel(const float* __restrict__ x,
                               const float* __restrict__ w,
                               unsigned short* __restrict__ xb,
                               unsigned short* __restrict__ wt) {
    __shared__ unsigned short tile[64][65];
    if (blockIdx.x < WTBLK) {
        const int kt = (blockIdx.x % 18) * 64, nt = (blockIdx.x / 18) * 64;
        #pragma unroll
        for (int i = 0; i < 16; ++i) {
            int idx = i * 256 + threadIdx.x;
            int kl = idx >> 6, nl = idx & 63;
            tile[kl][nl] = bf16_rne(w[(size_t)(kt + kl) * CO + nt + nl]);
        }
        __syncthreads();
        #pragma unroll
        for (int i = 0; i < 16; ++i) {
            int idx = i * 256 + threadIdx.x;
            int nl = idx >> 6, kl = idx & 63;
            wt[(size_t)(nt + nl) * K_DIM + kt + kl] = tile[kl][nl];
        }
    } else {
        const int t   = (blockIdx.x - WTBLK) * 256 + threadIdx.x;
        const int pix = t >> 4;
        const int cc  = (t & 15) << 3;
        const int b   = pix / (HPAD * HPAD);
        const int rem = pix % (HPAD * HPAD);
        const int hp  = rem / HPAD, wp = rem % HPAD;
        ushortx8 g = {0, 0, 0, 0, 0, 0, 0, 0};
        if (hp >= 1 && hp <= 56 && wp >= 1 && wp <= 56) {
            const float* s = x + ((size_t)((b * 56 + hp - 1) * 56 + (wp - 1))) * CI + cc;
            floatx4 f0 = ((const floatx4*)s)[0];
            floatx4 f1 = ((const floatx4*)s)[1];
            #pragma unroll
            for (int e = 0; e < 4; ++e) { g[e] = bf16_rne(f0[e]); g[e + 4] = bf16_rne(f1[e]); }
        }
        *(ushortx8*)(xb + (size_t)pix * CI + cc) = g;
    }
}

// ---- main: implicit-GEMM conv, 256x256 tile, phase-split schedule.
// K = 36 K-half slots (K=32); LDS = ring of 4 planes ([256][32] bf16 packed)
// per operand, 128 KB total. Depth-3 prefetch. Per slot, two phases:
//   phase A: { ds_read B + A-half0 (before barrier); vmcnt(4) confirming slot
//              s+1 (one full slot before its reads; never 0 until s=34);
//              stageA(s+3) -> plane (s-1)&3 (reads of that plane were consumed
//              before the previous slot's end barrier);
//              s_barrier; 16 MFMA under setprio; s_barrier }
//   phase B: { ds_read A-half1; stageB(s+3); s_barrier; 16 MFMA; s_barrier }
// Compiler inserts fine-grained lgkmcnt between ds_read and MFMA (C++ loads).
// Rolled main loop (33 iters) + 3 tail slots: small body, clean codegen.
// Rotation chunk swizzle kept (measured 0 bank conflicts).
__global__ __launch_bounds__(512, 2)
void conv_gemm_kernel(const unsigned short* __restrict__ xb,
                      const unsigned short* __restrict__ wt,
                      const float* __restrict__ bias,
                      float* __restrict__ out) {
    __shared__ unsigned short As[4][BM * 32];   // plane = slot & 3
    __shared__ unsigned short Bs[4][BN * 32];

    const int tid  = threadIdx.x;
    const int bid  = blockIdx.x;
    const int by   = (bid & 7) * (GRID_M / 8) + (bid >> 3);  // XCD-contiguous m-tiles
    const int wid  = tid >> 6;               // 0..7
    const int lane = tid & 63;
    const int lrow = lane & 15;
    const int quad = lane >> 4;
    const int wm   = (wid & 1) * 128;        // wave rows: 128 of 256
    const int wn   = (wid >> 1) * 64;        // wave cols: 64 of 256

    const int rseg = lane >> 2;
    const int cglb = ((lane & 3) - (rseg >> 1)) & 3;

    // global row bases for the two 128-row GLD rounds
    const unsigned short* aga[2];
    const unsigned short* bga[2];
    #pragma unroll
    for (int g = 0; g < 2; ++g) {
        const int m0 = by * BM + g * 128 + wid * 16 + rseg;
        const int b0 = m0 / 3136, r0 = m0 % 3136;
        aga[g] = xb + ((size_t)((b0 * HPAD + r0 / 56) * HPAD + r0 % 56)) * CI + cglb * 8;
        const int n0 = g * 128 + wid * 16 + rseg;
        bga[g] = wt + (size_t)n0 * K_DIM + cglb * 8;
    }
    const int wbase = wid * 512;             // (wid*16)*32 elements within a plane

    // fragment read offsets within a [256][32] plane
    const int swz = ((quad + (lrow >> 1)) & 3) * 8;
    int arow[8], brow[4];
    #pragma unroll
    for (int i = 0; i < 8; ++i) arow[i] = (wm + i * 16 + lrow) * 32 + swz;
    #pragma unroll
    for (int i = 0; i < 4; ++i) brow[i] = (wn + i * 16 + lrow) * 32 + swz;

    floatx4 acc[8][4] = {};

    auto stageA = [&](int u) {               // A K-half of slot u -> plane u&3
        const int p    = u >> 2;             // patch 0..8
        const int aoff = (p / 3 * HPAD + p % 3) * CI + (u & 3) * 32;
        GLD16(aga[0] + aoff, &As[u & 3][wbase]);
        GLD16(aga[1] + aoff, &As[u & 3][4096 + wbase]);
    };
    auto stageB = [&](int u) {
        const int boff = u * 32;
        GLD16(bga[0] + boff, &Bs[u & 3][wbase]);
        GLD16(bga[1] + boff, &Bs[u & 3][4096 + wbase]);
    };

    ushortx8 bfr[4], afr[4];
    auto rdB = [&](int P) {
        #pragma unroll
        for (int ni = 0; ni < 4; ++ni) bfr[ni] = *(const ushortx8*)&Bs[P][brow[ni]];
    };
    auto rdA = [&](int P, int h) {
        #pragma unroll
        for (int i = 0; i < 4; ++i) afr[i] = *(const ushortx8*)&As[P][arow[h * 4 + i]];
    };
    auto mm = [&](int h) {
        __builtin_amdgcn_s_setprio(1);
        #pragma unroll
        for (int i = 0; i < 4; ++i)
            #pragma unroll
            for (int ni = 0; ni < 4; ++ni)
                acc[h * 4 + i][ni] = __builtin_amdgcn_mfma_f32_16x16x32_bf16(
                    __builtin_bit_cast(bf16x8, afr[i]),
                    __builtin_bit_cast(bf16x8, bfr[ni]),
                    acc[h * 4 + i][ni], 0, 0, 0);
        __builtin_amdgcn_s_setprio(0);
    };

    // prologue: slots 0,1,2 in flight (12 loads); vmcnt(8) confirms slot 0
    // (leaves 1,2 in flight); barrier makes it workgroup-wide pre-read.
    stageA(0); stageB(0);
    stageA(1); stageB(1);
    stageA(2); stageB(2);
    asm volatile("s_waitcnt vmcnt(8)" ::: "memory");
    __builtin_amdgcn_s_barrier();

    #pragma unroll 1
    for (int s = 0; s < NSLOT - 3; ++s) {    // s = 0..32, stages slot s+3
        const int P = s & 3;
        rdB(P); rdA(P, 0);
        asm volatile("s_waitcnt vmcnt(4)" ::: "memory");
        stageA(s + 3);
        __builtin_amdgcn_s_barrier();
        mm(0);
        __builtin_amdgcn_s_barrier();
        rdA(P, 1);
        stageB(s + 3);
        __builtin_amdgcn_s_barrier();
        mm(1);
        __builtin_amdgcn_s_barrier();
    }
    // s = 33: confirm slot 34 (leave 35's 4 loads in flight), no stage
    {
        rdB(1); rdA(1, 0);
        asm volatile("s_waitcnt vmcnt(4)" ::: "memory");
        __builtin_amdgcn_s_barrier();
        mm(0);
        __builtin_amdgcn_s_barrier();
        rdA(1, 1);
        __builtin_amdgcn_s_barrier();
        mm(1);
        __builtin_amdgcn_s_barrier();
    }
    // s = 34: tail drain, confirm slot 35
    {
        rdB(2); rdA(2, 0);
        asm volatile("s_waitcnt vmcnt(0)" ::: "memory");
        __builtin_amdgcn_s_barrier();
        mm(0);
        __builtin_amdgcn_s_barrier();
        rdA(2, 1);
        __builtin_amdgcn_s_barrier();
        mm(1);
        __builtin_amdgcn_s_barrier();
    }
    // s = 35: everything resident
    {
        rdB(3); rdA(3, 0);
        mm(0);
        rdA(3, 1);
        mm(1);
    }

    // epilogue: bias + store (C/D: col=lane&15, row=quad*4+r)
    float bv[4];
    #pragma unroll
    for (int ni = 0; ni < 4; ++ni)
        bv[ni] = bias[wn + ni * 16 + lrow];

    #pragma unroll
    for (int mi = 0; mi < 8; ++mi) {
        #pragma unroll
        for (int r = 0; r < 4; ++r) {
            const int row = by * BM + wm + mi * 16 + quad * 4 + r;
            float* o = out + (size_t)row * CO + wn + lrow;
            #pragma unroll
            for (int ni = 0; ni < 4; ++ni)
                o[ni * 16] = acc[mi][ni][r] + bv[ni];
        }
    }
}

extern "C" void kernel_launch(void* const* d_in, const int* in_sizes, int n_in,
                              void* d_out, int out_size, void* d_ws, size_t ws_size,
                              hipStream_t stream) {
    (void)in_sizes; (void)n_in; (void)out_size; (void)ws_size;
    const float* x    = (const float*)d_in[0];
    const float* w    = (const float*)d_in[1];
    const float* bias = (const float*)d_in[2];
    float* out = (float*)d_out;

    unsigned short* wt = (unsigned short*)d_ws;                     // bf16 [256][1152]
    unsigned short* xb = (unsigned short*)((char*)d_ws + XB_OFF);   // bf16 [32][58][58][128]

    prepass_kernel<<<dim3(WTBLK + XPBLK), dim3(256), 0, stream>>>(x, w, xb, wt);
    conv_gemm_kernel<<<dim3(GRID_M), dim3(512), 0, stream>>>(xb, wt, bias, out);
}

// Round 6
// 203.924 us; speedup vs baseline: 1.1041x; 1.1041x over previous
//
#include <hip/hip_runtime.h>

#define B_ 32
#define CI 128
#define CO 256
#define K_DIM 1152            // 9*128
#define M_DIM 100352          // 32*56*56
#define BM 128
#define BN 128
#define KT 18                 // K-tiles of 64 (2 slots of 32 each)
#define HPAD 58               // 56 + halo
#define XB_OFF 589824         // byte offset of xb in ws (after wt: 1152*256*2 B)
#define WTBLK 72              // (K_DIM/64)*(CO/64) transpose tiles
#define XPBLK 6728            // (B_*HPAD*HPAD*16)/256 pad blocks
#define GRID_M 784            // M_DIM / BM = 98*8 (divisible by 8 XCDs)

typedef float          floatx4  __attribute__((ext_vector_type(4)));
typedef unsigned short ushortx8 __attribute__((ext_vector_type(8)));
typedef __bf16         bf16x8   __attribute__((ext_vector_type(8)));

typedef __attribute__((address_space(1))) void gas_void;
typedef __attribute__((address_space(3))) void las_void;
#define GLD16(g, l) __builtin_amdgcn_global_load_lds( \
    (gas_void*)(uintptr_t)(g), (las_void*)(l), 16, 0, 0)

__device__ __forceinline__ unsigned short bf16_rne(float f) {
    unsigned u = __builtin_bit_cast(unsigned, f);
    u += 0x7FFFu + ((u >> 16) & 1u);
    return (unsigned short)(u >> 16);
}

// ---- fused prepass: blocks [0,72) transpose w -> wt bf16 [256][1152];
//      blocks [72, 72+6728) pad x -> xb bf16 [32][58][58][128] with zero halo.
__global__ void prepass_kernel(const float* __restrict__ x,
                               const float* __restrict__ w,
                               unsigned short* __restrict__ xb,
                               unsigned short* __restrict__ wt) {
    __shared__ unsigned short tile[64][65];
    if (blockIdx.x < WTBLK) {
        const int kt = (blockIdx.x % 18) * 64, nt = (blockIdx.x / 18) * 64;
        #pragma unroll
        for (int i = 0; i < 16; ++i) {
            int idx = i * 256 + threadIdx.x;
            int kl = idx >> 6, nl = idx & 63;
            tile[kl][nl] = bf16_rne(w[(size_t)(kt + kl) * CO + nt + nl]);
        }
        __syncthreads();
        #pragma unroll
        for (int i = 0; i < 16; ++i) {
            int idx = i * 256 + threadIdx.x;
            int nl = idx >> 6, kl = idx & 63;
            wt[(size_t)(nt + nl) * K_DIM + kt + kl] = tile[kl][nl];
        }
    } else {
        const int t   = (blockIdx.x - WTBLK) * 256 + threadIdx.x;
        const int pix = t >> 4;
        const int cc  = (t & 15) << 3;
        const int b   = pix / (HPAD * HPAD);
        const int rem = pix % (HPAD * HPAD);
        const int hp  = rem / HPAD, wp = rem % HPAD;
        ushortx8 g = {0, 0, 0, 0, 0, 0, 0, 0};
        if (hp >= 1 && hp <= 56 && wp >= 1 && wp <= 56) {
            const float* s = x + ((size_t)((b * 56 + hp - 1) * 56 + (wp - 1))) * CI + cc;
            floatx4 f0 = ((const floatx4*)s)[0];
            floatx4 f1 = ((const floatx4*)s)[1];
            #pragma unroll
            for (int e = 0; e < 4; ++e) { g[e] = bf16_rne(f0[e]); g[e + 4] = bf16_rne(f1[e]); }
        }
        *(ushortx8*)(xb + (size_t)pix * CI + cc) = g;
    }
}

// ---- main: implicit-GEMM conv, m97-style TLP structure.
// 128x128 tile, 4 waves (2Mx2N, 64x64 each), BK=64 as 2 verified [128][32]
// planes per operand. SINGLE-buffered 32 KB LDS -> 4 blocks/CU at
// __launch_bounds__(256,4): cross-block TLP does the pipelining (m114
// mechanism; explicit dbuf measured-neutral on top of it). Simplest possible
// schedule: { stage 8 GLD16; sync; compute 32 MFMA; sync } per K-tile,
// 2 barriers/tile. No setprio (lockstep regime), no manual vmcnt.
// Rotation chunk swizzle + fragment offsets + C/D mapping carried over
// verbatim from the verified kernels (0 bank conflicts, absmax 0.0625).
__global__ __launch_bounds__(256, 4)
void conv_gemm_kernel(const unsigned short* __restrict__ xb,
                      const unsigned short* __restrict__ wt,
                      const float* __restrict__ bias,
                      float* __restrict__ out) {
    __shared__ unsigned short As[2][BM * 32];   // [kk][row*32+chunk], 2 x 8 KB
    __shared__ unsigned short Bs[2][BN * 32];   // 2 x 8 KB  (total 32 KB)

    const int tid  = threadIdx.x;
    const int bx   = blockIdx.y;             // n tile 0..1
    const int bid  = blockIdx.x;
    const int by   = (bid & 7) * (GRID_M / 8) + (bid >> 3);  // XCD-contiguous m-tiles
    const int wid  = tid >> 6;               // 0..3
    const int lane = tid & 63;
    const int lrow = lane & 15;
    const int quad = lane >> 4;
    const int wm   = (wid & 1) * 64;         // wave rows: 64 of 128
    const int wn   = (wid >> 1) * 64;        // wave cols: 64 of 128

    // staging lane mapping (verified): seg-row = lane>>2, slot = lane&3,
    // fetch global chunk (slot - (rseg>>1)) & 3
    const int rseg = lane >> 2;
    const int cglb = ((lane & 3) - (rseg >> 1)) & 3;

    // global row bases: round r covers rows r*64 + wid*16 + rseg
    const unsigned short* aga[2];
    const unsigned short* bga[2];
    #pragma unroll
    for (int g = 0; g < 2; ++g) {
        const int m0 = by * BM + g * 64 + wid * 16 + rseg;
        const int b0 = m0 / 3136, r0 = m0 % 3136;
        aga[g] = xb + ((size_t)((b0 * HPAD + r0 / 56) * HPAD + r0 % 56)) * CI + cglb * 8;
        const int n0 = bx * BN + g * 64 + wid * 16 + rseg;
        bga[g] = wt + (size_t)n0 * K_DIM + cglb * 8;
    }
    const int wb0 = (wid * 16) * 32;         // LDS base, round 0
    const int wb1 = (64 + wid * 16) * 32;    // LDS base, round 1

    // fragment read offsets within a [128][32] plane (verified)
    const int swz = ((quad + (lrow >> 1)) & 3) * 8;
    int arow[4], brow[4];
    #pragma unroll
    for (int i = 0; i < 4; ++i) {
        arow[i] = (wm + i * 16 + lrow) * 32 + swz;
        brow[i] = (wn + i * 16 + lrow) * 32 + swz;
    }

    floatx4 acc[4][4] = {};

    // stage K-slot u (= 2t+kk, K-offset u*32) into plane kk = u&1 of tile
    auto stageA = [&](int u, int kk) {
        const int p    = u >> 2;             // patch 0..8
        const int aoff = (p / 3 * HPAD + p % 3) * CI + (u & 3) * 32;
        GLD16(aga[0] + aoff, &As[kk][wb0]);
        GLD16(aga[1] + aoff, &As[kk][wb1]);
    };
    auto stageB = [&](int u, int kk) {
        const int boff = u * 32;
        GLD16(bga[0] + boff, &Bs[kk][wb0]);
        GLD16(bga[1] + boff, &Bs[kk][wb1]);
    };

    ushortx8 bfr[4], afr[4];
    auto compute = [&](int kk) {
        #pragma unroll
        for (int ni = 0; ni < 4; ++ni) bfr[ni] = *(const ushortx8*)&Bs[kk][brow[ni]];
        #pragma unroll
        for (int i = 0; i < 4; ++i) afr[i] = *(const ushortx8*)&As[kk][arow[i]];
        #pragma unroll
        for (int i = 0; i < 4; ++i)
            #pragma unroll
            for (int ni = 0; ni < 4; ++ni)
                acc[i][ni] = __builtin_amdgcn_mfma_f32_16x16x32_bf16(
                    __builtin_bit_cast(bf16x8, afr[i]),
                    __builtin_bit_cast(bf16x8, bfr[ni]),
                    acc[i][ni], 0, 0, 0);
    };

    #pragma unroll 1
    for (int t = 0; t < KT; ++t) {
        const int u = t * 2;
        stageA(u, 0); stageB(u, 0);
        stageA(u + 1, 1); stageB(u + 1, 1);
        __syncthreads();                     // publishes tile t (drains vmcnt)
        compute(0);
        compute(1);
        __syncthreads();                     // reads done before next stage
    }

    // epilogue: bias + store (C/D: col=lane&15, row=quad*4+r)
    float bv[4];
    #pragma unroll
    for (int ni = 0; ni < 4; ++ni)
        bv[ni] = bias[bx * BN + wn + ni * 16 + lrow];

    #pragma unroll
    for (int mi = 0; mi < 4; ++mi) {
        #pragma unroll
        for (int r = 0; r < 4; ++r) {
            const int row = by * BM + wm + mi * 16 + quad * 4 + r;
            float* o = out + (size_t)row * CO + bx * BN + wn + lrow;
            #pragma unroll
            for (int ni = 0; ni < 4; ++ni)
                o[ni * 16] = acc[mi][ni][r] + bv[ni];
        }
    }
}

extern "C" void kernel_launch(void* const* d_in, const int* in_sizes, int n_in,
                              void* d_out, int out_size, void* d_ws, size_t ws_size,
                              hipStream_t stream) {
    (void)in_sizes; (void)n_in; (void)out_size; (void)ws_size;
    const float* x    = (const float*)d_in[0];
    const float* w    = (const float*)d_in[1];
    const float* bias = (const float*)d_in[2];
    float* out = (float*)d_out;

    unsigned short* wt = (unsigned short*)d_ws;                     // bf16 [256][1152]
    unsigned short* xb = (unsigned short*)((char*)d_ws + XB_OFF);   // bf16 [32][58][58][128]

    prepass_kernel<<<dim3(WTBLK + XPBLK), dim3(256), 0, stream>>>(x, w, xb, wt);
    conv_gemm_kernel<<<dim3(GRID_M, CO / BN), dim3(256), 0, stream>>>(xb, wt, bias, out);
}